// Round 1
// baseline (151.236 us; speedup 1.0000x reference)
//
#include <hip/hip_runtime.h>
#include <math.h>

#define NG  256   // graphs
#define NN  64    // nodes per graph
#define KK  24    // kNN
#define HID 128
#define FP  132   // padded LDS row (floats): 132*4=528 B, 16B-aligned, spreads banks

__device__ __forceinline__ float elu1(float x) {
    return x > 0.0f ? x : (expf(x) - 1.0f);
}

extern "C" __global__ void __launch_bounds__(256, 1)
dgcnn_kernel(const float* __restrict__ x_pf,
             const float* __restrict__ W1, const float* __restrict__ b1,
             const float* __restrict__ W2, const float* __restrict__ b2,
             const float* __restrict__ Wc, const float* __restrict__ bc,
             const float* __restrict__ Wo1, const float* __restrict__ bo1,
             const float* __restrict__ Wo2, const float* __restrict__ bo2,
             const float* __restrict__ Wo3, const float* __restrict__ bo3,
             const float* __restrict__ Wo4, const float* __restrict__ bo4,
             float* __restrict__ out)
{
    __shared__ float feat[NN * FP];   // current node features (overwritten per layer)
    __shared__ float Ub[NN * FP];     // scratch: h1, then U = feat@A per layer
    __shared__ float Vb[NN * FP];     // scratch: V = feat@B per layer
    __shared__ float dmat[NN * 65];   // pairwise distances (row pad 65 -> conflict-free scan)
    __shared__ int   knn[NN * KK];
    __shared__ float xin[NN * 16];
    __shared__ float sq[NN];
    __shared__ float pooled[HID];
    __shared__ float r1[64];
    __shared__ float r2[32];
    __shared__ float r3[32];

    const int tid = threadIdx.x;
    const int g   = blockIdx.x;

    // ---- load x (64 x 15) ----
    for (int i = tid; i < NN * 15; i += 256) {
        xin[(i / 15) * 16 + (i % 15)] = x_pf[g * NN * 15 + i];
    }
    __syncthreads();

    const int hq = (tid & 31);   // h-quad: h = hq*4
    const int ng = (tid >> 5);   // node group: n = ng*8 + r
    const int h0 = hq * 4;
    const int n0 = ng * 8;

    // ---- h1 = elu(x @ W1 + b1) -> Ub ----
    {
        float acc[8][4];
        float4 bv = *(const float4*)(b1 + h0);
        #pragma unroll
        for (int r = 0; r < 8; ++r) { acc[r][0]=bv.x; acc[r][1]=bv.y; acc[r][2]=bv.z; acc[r][3]=bv.w; }
        #pragma unroll
        for (int f = 0; f < 15; ++f) {
            float4 w = *(const float4*)(W1 + f * HID + h0);
            #pragma unroll
            for (int r = 0; r < 8; ++r) {
                float xv = xin[(n0 + r) * 16 + f];
                acc[r][0] += xv * w.x; acc[r][1] += xv * w.y;
                acc[r][2] += xv * w.z; acc[r][3] += xv * w.w;
            }
        }
        #pragma unroll
        for (int r = 0; r < 8; ++r) {
            float4 o;
            o.x = elu1(acc[r][0]); o.y = elu1(acc[r][1]);
            o.z = elu1(acc[r][2]); o.w = elu1(acc[r][3]);
            *(float4*)(Ub + (n0 + r) * FP + h0) = o;
        }
    }
    __syncthreads();

    // ---- feat = elu(Ub @ W2 + b2) ----
    {
        float acc[8][4];
        float4 bv = *(const float4*)(b2 + h0);
        #pragma unroll
        for (int r = 0; r < 8; ++r) { acc[r][0]=bv.x; acc[r][1]=bv.y; acc[r][2]=bv.z; acc[r][3]=bv.w; }
        for (int f4 = 0; f4 < 32; ++f4) {
            float4 w0 = *(const float4*)(W2 + (f4*4+0) * HID + h0);
            float4 w1 = *(const float4*)(W2 + (f4*4+1) * HID + h0);
            float4 w2 = *(const float4*)(W2 + (f4*4+2) * HID + h0);
            float4 w3 = *(const float4*)(W2 + (f4*4+3) * HID + h0);
            #pragma unroll
            for (int r = 0; r < 8; ++r) {
                float4 xv = *(const float4*)(Ub + (n0 + r) * FP + f4 * 4);
                acc[r][0] += xv.x*w0.x + xv.y*w1.x + xv.z*w2.x + xv.w*w3.x;
                acc[r][1] += xv.x*w0.y + xv.y*w1.y + xv.z*w2.y + xv.w*w3.y;
                acc[r][2] += xv.x*w0.z + xv.y*w1.z + xv.z*w2.z + xv.w*w3.z;
                acc[r][3] += xv.x*w0.w + xv.y*w1.w + xv.z*w2.w + xv.w*w3.w;
            }
        }
        #pragma unroll
        for (int r = 0; r < 8; ++r) {
            float4 o;
            o.x = elu1(acc[r][0]); o.y = elu1(acc[r][1]);
            o.z = elu1(acc[r][2]); o.w = elu1(acc[r][3]);
            *(float4*)(feat + (n0 + r) * FP + h0) = o;
        }
    }
    __syncthreads();

    // ==== 3 EdgeConv layers ====
    for (int layer = 0; layer < 3; ++layer) {
        // -- squared norms --
        if (tid < NN) {
            float s = 0.f;
            for (int f4 = 0; f4 < 32; ++f4) {
                float4 v = *(const float4*)(feat + tid * FP + f4 * 4);
                s += v.x*v.x + v.y*v.y + v.z*v.z + v.w*v.w;
            }
            sq[tid] = s;
        }
        __syncthreads();

        // -- pairwise distances: d = sq[n] + sq[m] - 2 * dot --
        {
            const int mq = (tid & 15) * 4;
            const int nq = (tid >> 4) * 4;
            float acc[4][4] = {{0.f}};
            for (int f4 = 0; f4 < 32; ++f4) {
                float4 a[4], b[4];
                #pragma unroll
                for (int i = 0; i < 4; ++i) a[i] = *(const float4*)(feat + (nq + i) * FP + f4 * 4);
                #pragma unroll
                for (int j = 0; j < 4; ++j) b[j] = *(const float4*)(feat + (mq + j) * FP + f4 * 4);
                #pragma unroll
                for (int i = 0; i < 4; ++i)
                    #pragma unroll
                    for (int j = 0; j < 4; ++j)
                        acc[i][j] += a[i].x*b[j].x + a[i].y*b[j].y + a[i].z*b[j].z + a[i].w*b[j].w;
            }
            #pragma unroll
            for (int i = 0; i < 4; ++i)
                #pragma unroll
                for (int j = 0; j < 4; ++j)
                    dmat[(nq + i) * 65 + (mq + j)] = sq[nq + i] + sq[mq + j] - 2.0f * acc[i][j];
        }
        __syncthreads();

        // -- kNN selection: K smallest, ties -> lower index (matches lax.top_k on -d) --
        if (tid < NN) {
            float* row = dmat + tid * 65;
            for (int k = 0; k < KK; ++k) {
                float best = 1e30f; int bi = 0;
                for (int m = 0; m < NN; ++m) {
                    float v = row[m];
                    if (v < best) { best = v; bi = m; }
                }
                knn[tid * KK + k] = bi;
                row[bi] = 1e30f;
            }
        }
        __syncthreads();

        // -- U = feat @ Wc[:128], V = feat @ Wc[128:] --
        {
            float au[8][4] = {{0.f}};
            float av[8][4] = {{0.f}};
            for (int f4 = 0; f4 < 32; ++f4) {
                float4 xr[8];
                #pragma unroll
                for (int r = 0; r < 8; ++r) xr[r] = *(const float4*)(feat + (n0 + r) * FP + f4 * 4);
                #pragma unroll
                for (int j = 0; j < 4; ++j) {
                    float4 wa = *(const float4*)(Wc + (f4*4 + j) * HID + h0);
                    float4 wb = *(const float4*)(Wc + (HID + f4*4 + j) * HID + h0);
                    #pragma unroll
                    for (int r = 0; r < 8; ++r) {
                        float xv = (j == 0) ? xr[r].x : (j == 1) ? xr[r].y : (j == 2) ? xr[r].z : xr[r].w;
                        au[r][0] += xv * wa.x; au[r][1] += xv * wa.y;
                        au[r][2] += xv * wa.z; au[r][3] += xv * wa.w;
                        av[r][0] += xv * wb.x; av[r][1] += xv * wb.y;
                        av[r][2] += xv * wb.z; av[r][3] += xv * wb.w;
                    }
                }
            }
            #pragma unroll
            for (int r = 0; r < 8; ++r) {
                float4 ou, ov;
                ou.x = au[r][0]; ou.y = au[r][1]; ou.z = au[r][2]; ou.w = au[r][3];
                ov.x = av[r][0]; ov.y = av[r][1]; ov.z = av[r][2]; ov.w = av[r][3];
                *(float4*)(Ub + (n0 + r) * FP + h0) = ou;
                *(float4*)(Vb + (n0 + r) * FP + h0) = ov;
            }
        }
        __syncthreads();

        // -- out[n,h] = elu(U - V_self + bc + max_k V[knn]) -> feat (overwrite) --
        {
            float4 bcv = *(const float4*)(bc + h0);
            #pragma unroll
            for (int r = 0; r < 8; ++r) {
                const int n = n0 + r;
                float4 mx = make_float4(-1e30f, -1e30f, -1e30f, -1e30f);
                for (int k = 0; k < KK; ++k) {
                    int j = knn[n * KK + k];
                    float4 v = *(const float4*)(Vb + j * FP + h0);
                    mx.x = fmaxf(mx.x, v.x); mx.y = fmaxf(mx.y, v.y);
                    mx.z = fmaxf(mx.z, v.z); mx.w = fmaxf(mx.w, v.w);
                }
                float4 u  = *(const float4*)(Ub + n * FP + h0);
                float4 vn = *(const float4*)(Vb + n * FP + h0);
                float4 o;
                o.x = elu1(u.x - vn.x + bcv.x + mx.x);
                o.y = elu1(u.y - vn.y + bcv.y + mx.y);
                o.z = elu1(u.z - vn.z + bcv.z + mx.z);
                o.w = elu1(u.w - vn.w + bcv.w + mx.w);
                *(float4*)(feat + n * FP + h0) = o;
            }
        }
        __syncthreads();
    }

    // ==== pooled = sum over nodes ====
    if (tid < HID) {
        float s = 0.f;
        for (int n = 0; n < NN; ++n) s += feat[n * FP + tid];
        pooled[tid] = s;
    }
    __syncthreads();

    // ==== head MLP ====
    if (tid < 64) {
        float a = bo1[tid];
        for (int f = 0; f < HID; ++f) a += pooled[f] * Wo1[f * 64 + tid];
        r1[tid] = elu1(a);
    }
    __syncthreads();
    if (tid < 32) {
        float a = bo2[tid];
        for (int f = 0; f < 64; ++f) a += r1[f] * Wo2[f * 32 + tid];
        r2[tid] = elu1(a);
    }
    __syncthreads();
    if (tid < 32) {
        float a = bo3[tid];
        for (int f = 0; f < 32; ++f) a += r2[f] * Wo3[f * 32 + tid];
        r3[tid] = elu1(a);
    }
    __syncthreads();
    if (tid < 8) {
        float a = bo4[tid];
        for (int f = 0; f < 32; ++f) a += r3[f] * Wo4[f * 8 + tid];
        out[g * 8 + tid] = a;
    }

    // ==== output 1: batch_pf (value = graph index, exact in fp32) ====
    if (tid < NN) {
        out[NG * 8 + g * NN + tid] = (float)g;
    }
}

extern "C" void kernel_launch(void* const* d_in, const int* in_sizes, int n_in,
                              void* d_out, int out_size, void* d_ws, size_t ws_size,
                              hipStream_t stream) {
    dgcnn_kernel<<<NG, 256, 0, stream>>>(
        (const float*)d_in[0],                            // x_pf
        (const float*)d_in[2],  (const float*)d_in[3],    // W1, b1
        (const float*)d_in[4],  (const float*)d_in[5],    // W2, b2
        (const float*)d_in[6],  (const float*)d_in[7],    // Wc, bc
        (const float*)d_in[8],  (const float*)d_in[9],    // Wo1, bo1
        (const float*)d_in[10], (const float*)d_in[11],   // Wo2, bo2
        (const float*)d_in[12], (const float*)d_in[13],   // Wo3, bo3
        (const float*)d_in[14], (const float*)d_in[15],   // Wo4, bo4
        (float*)d_out);
}

// Round 2
// 135.556 us; speedup vs baseline: 1.1157x; 1.1157x over previous
//
#include <hip/hip_runtime.h>
#include <math.h>

#define NG  256   // graphs
#define NN  64    // nodes per graph
#define KK  24    // kNN
#define HID 128
#define FP  132   // padded feature row (floats): 528 B, 16B-aligned, rows shift banks by 4
#define DP  68    // padded dmat row (floats): 272 B, 16B-aligned

__device__ __forceinline__ float elu1(float x) {
    return x > 0.0f ? x : (expf(x) - 1.0f);
}

extern "C" __global__ void __launch_bounds__(512, 1)
dgcnn_kernel(const float* __restrict__ x_pf,
             const float* __restrict__ W1, const float* __restrict__ b1,
             const float* __restrict__ W2, const float* __restrict__ b2,
             const float* __restrict__ Wc, const float* __restrict__ bc,
             const float* __restrict__ Wo1, const float* __restrict__ bo1,
             const float* __restrict__ Wo2, const float* __restrict__ bo2,
             const float* __restrict__ Wo3, const float* __restrict__ bo3,
             const float* __restrict__ Wo4, const float* __restrict__ bo4,
             float* __restrict__ out)
{
    __shared__ float feat[NN * FP];
    __shared__ float Ub[NN * FP];
    __shared__ float Vb[NN * FP];
    __shared__ float dmat[NN * DP];
    __shared__ int   knn[NN * KK];
    __shared__ float xin[NN * 16];
    __shared__ float sq[NN];
    __shared__ float pooled[HID];
    __shared__ float red[4 * HID];   // reduction scratch
    __shared__ float r1[64];
    __shared__ float r2[32];
    __shared__ float r3[32];

    const int tid = threadIdx.x;
    const int g   = blockIdx.x;

    // batch_pf output (independent of everything)
    if (tid < NN) out[NG * 8 + g * NN + tid] = (float)g;

    // ---- load x (64 x 15) ----
    for (int i = tid; i < NN * 15; i += 512) {
        xin[(i / 15) * 16 + (i % 15)] = x_pf[g * NN * 15 + i];
    }
    __syncthreads();

    const int hq = (tid & 31);   // h-quad: h = hq*4
    const int ng = (tid >> 5);   // node group (0..15)
    const int h0 = hq * 4;
    const int n0 = ng * 4;       // 4 nodes per thread

    // ---- h1 = elu(x @ W1 + b1) -> Ub ----
    {
        float acc[4][4];
        float4 bv = *(const float4*)(b1 + h0);
        #pragma unroll
        for (int r = 0; r < 4; ++r) { acc[r][0]=bv.x; acc[r][1]=bv.y; acc[r][2]=bv.z; acc[r][3]=bv.w; }
        #pragma unroll
        for (int f = 0; f < 15; ++f) {
            float4 w = *(const float4*)(W1 + f * HID + h0);
            #pragma unroll
            for (int r = 0; r < 4; ++r) {
                float xv = xin[(n0 + r) * 16 + f];
                acc[r][0] += xv * w.x; acc[r][1] += xv * w.y;
                acc[r][2] += xv * w.z; acc[r][3] += xv * w.w;
            }
        }
        #pragma unroll
        for (int r = 0; r < 4; ++r) {
            float4 o;
            o.x = elu1(acc[r][0]); o.y = elu1(acc[r][1]);
            o.z = elu1(acc[r][2]); o.w = elu1(acc[r][3]);
            *(float4*)(Ub + (n0 + r) * FP + h0) = o;
        }
    }
    __syncthreads();

    // ---- feat = elu(Ub @ W2 + b2) ----
    {
        float acc[4][4];
        float4 bv = *(const float4*)(b2 + h0);
        #pragma unroll
        for (int r = 0; r < 4; ++r) { acc[r][0]=bv.x; acc[r][1]=bv.y; acc[r][2]=bv.z; acc[r][3]=bv.w; }
        for (int f4 = 0; f4 < 32; ++f4) {
            float4 w0 = *(const float4*)(W2 + (f4*4+0) * HID + h0);
            float4 w1 = *(const float4*)(W2 + (f4*4+1) * HID + h0);
            float4 w2 = *(const float4*)(W2 + (f4*4+2) * HID + h0);
            float4 w3 = *(const float4*)(W2 + (f4*4+3) * HID + h0);
            #pragma unroll
            for (int r = 0; r < 4; ++r) {
                float4 xv = *(const float4*)(Ub + (n0 + r) * FP + f4 * 4);
                acc[r][0] += xv.x*w0.x + xv.y*w1.x + xv.z*w2.x + xv.w*w3.x;
                acc[r][1] += xv.x*w0.y + xv.y*w1.y + xv.z*w2.y + xv.w*w3.y;
                acc[r][2] += xv.x*w0.z + xv.y*w1.z + xv.z*w2.z + xv.w*w3.z;
                acc[r][3] += xv.x*w0.w + xv.y*w1.w + xv.z*w2.w + xv.w*w3.w;
            }
        }
        #pragma unroll
        for (int r = 0; r < 4; ++r) {
            float4 o;
            o.x = elu1(acc[r][0]); o.y = elu1(acc[r][1]);
            o.z = elu1(acc[r][2]); o.w = elu1(acc[r][3]);
            *(float4*)(feat + (n0 + r) * FP + h0) = o;
        }
    }
    __syncthreads();

    // ==== 3 EdgeConv layers ====
    for (int layer = 0; layer < 3; ++layer) {
        // -- squared norms: 4 threads per row --
        if (tid < 256) {
            const int row = tid >> 2;
            const int q   = tid & 3;
            float s = 0.f;
            for (int f4 = q * 8; f4 < q * 8 + 8; ++f4) {
                float4 v = *(const float4*)(feat + row * FP + f4 * 4);
                s += v.x*v.x + v.y*v.y + v.z*v.z + v.w*v.w;
            }
            s += __shfl_xor(s, 1, 64);
            s += __shfl_xor(s, 2, 64);
            if (q == 0) sq[row] = s;
        }
        __syncthreads();

        // -- pairwise distances: each thread 2n x 4m (m strided by 16 -> 2-way banks) --
        {
            const int nb = tid >> 4;        // 0..31
            const int mg = tid & 15;
            float acc[2][4] = {{0.f}};
            for (int f4 = 0; f4 < 32; ++f4) {
                float4 a0 = *(const float4*)(feat + nb * FP + f4 * 4);
                float4 a1 = *(const float4*)(feat + (nb + 32) * FP + f4 * 4);
                #pragma unroll
                for (int j = 0; j < 4; ++j) {
                    float4 b = *(const float4*)(feat + (mg + 16 * j) * FP + f4 * 4);
                    acc[0][j] += a0.x*b.x + a0.y*b.y + a0.z*b.z + a0.w*b.w;
                    acc[1][j] += a1.x*b.x + a1.y*b.y + a1.z*b.z + a1.w*b.w;
                }
            }
            #pragma unroll
            for (int j = 0; j < 4; ++j) {
                const int m = mg + 16 * j;
                dmat[nb * DP + m]        = sq[nb]      + sq[m] - 2.0f * acc[0][j];
                dmat[(nb + 32) * DP + m] = sq[nb + 32] + sq[m] - 2.0f * acc[1][j];
            }
        }
        __syncthreads();

        // -- kNN membership via rank counting (ties -> lower index, == stable top_k) --
        {
            const int wv   = tid >> 6;   // wave 0..7
            const int lane = tid & 63;
            for (int p = 0; p < 8; ++p) {
                const int r = wv * 8 + p;
                const float dm = dmat[r * DP + lane];
                float4 rv[16];
                #pragma unroll
                for (int q = 0; q < 16; ++q) rv[q] = *(const float4*)(dmat + r * DP + q * 4);
                int rank = 0;
                #pragma unroll
                for (int q = 0; q < 16; ++q) {
                    const int m0 = q * 4;
                    rank += (rv[q].x < dm) || (rv[q].x == dm && (m0 + 0) < lane);
                    rank += (rv[q].y < dm) || (rv[q].y == dm && (m0 + 1) < lane);
                    rank += (rv[q].z < dm) || (rv[q].z == dm && (m0 + 2) < lane);
                    rank += (rv[q].w < dm) || (rv[q].w == dm && (m0 + 3) < lane);
                }
                const unsigned long long mask = __ballot(rank < KK);
                if (rank < KK) {
                    const int c = __popcll(mask & ((1ULL << lane) - 1ULL));
                    knn[r * KK + c] = lane;
                }
            }
        }
        __syncthreads();

        // -- U = feat @ Wc[:128], V = feat @ Wc[128:] --
        {
            float au[4][4] = {{0.f}};
            float av[4][4] = {{0.f}};
            for (int f4 = 0; f4 < 32; ++f4) {
                float4 xr[4];
                #pragma unroll
                for (int r = 0; r < 4; ++r) xr[r] = *(const float4*)(feat + (n0 + r) * FP + f4 * 4);
                #pragma unroll
                for (int j = 0; j < 4; ++j) {
                    float4 wa = *(const float4*)(Wc + (f4*4 + j) * HID + h0);
                    float4 wb = *(const float4*)(Wc + (HID + f4*4 + j) * HID + h0);
                    #pragma unroll
                    for (int r = 0; r < 4; ++r) {
                        float xv = (j == 0) ? xr[r].x : (j == 1) ? xr[r].y : (j == 2) ? xr[r].z : xr[r].w;
                        au[r][0] += xv * wa.x; au[r][1] += xv * wa.y;
                        au[r][2] += xv * wa.z; au[r][3] += xv * wa.w;
                        av[r][0] += xv * wb.x; av[r][1] += xv * wb.y;
                        av[r][2] += xv * wb.z; av[r][3] += xv * wb.w;
                    }
                }
            }
            #pragma unroll
            for (int r = 0; r < 4; ++r) {
                float4 ou, ov;
                ou.x = au[r][0]; ou.y = au[r][1]; ou.z = au[r][2]; ou.w = au[r][3];
                ov.x = av[r][0]; ov.y = av[r][1]; ov.z = av[r][2]; ov.w = av[r][3];
                *(float4*)(Ub + (n0 + r) * FP + h0) = ou;
                *(float4*)(Vb + (n0 + r) * FP + h0) = ov;
            }
        }
        __syncthreads();

        // -- feat[n,h] = elu(U - V_self + bc + max_k V[knn]) --
        {
            float4 bcv = *(const float4*)(bc + h0);
            #pragma unroll
            for (int r = 0; r < 4; ++r) {
                const int n = n0 + r;
                float4 mx = make_float4(-1e30f, -1e30f, -1e30f, -1e30f);
                for (int k = 0; k < KK; ++k) {
                    int j = knn[n * KK + k];
                    float4 v = *(const float4*)(Vb + j * FP + h0);
                    mx.x = fmaxf(mx.x, v.x); mx.y = fmaxf(mx.y, v.y);
                    mx.z = fmaxf(mx.z, v.z); mx.w = fmaxf(mx.w, v.w);
                }
                float4 u  = *(const float4*)(Ub + n * FP + h0);
                float4 vn = *(const float4*)(Vb + n * FP + h0);
                float4 o;
                o.x = elu1(u.x - vn.x + bcv.x + mx.x);
                o.y = elu1(u.y - vn.y + bcv.y + mx.y);
                o.z = elu1(u.z - vn.z + bcv.z + mx.z);
                o.w = elu1(u.w - vn.w + bcv.w + mx.w);
                *(float4*)(feat + n * FP + h0) = o;
            }
        }
        __syncthreads();
    }

    // ==== pooled = sum over nodes (4 partials per channel) ====
    {
        const int pq = tid >> 7;        // 0..3
        const int ch = tid & 127;
        float s = 0.f;
        for (int n = pq * 16; n < pq * 16 + 16; ++n) s += feat[n * FP + ch];
        red[pq * HID + ch] = s;
    }
    __syncthreads();
    if (tid < HID) {
        pooled[tid] = red[tid] + red[HID + tid] + red[2 * HID + tid] + red[3 * HID + tid];
    }
    __syncthreads();

    // ==== head MLP ====
    if (tid < 256) {
        const int o = tid & 63, part = tid >> 6;
        float s = 0.f;
        for (int f = part * 32; f < part * 32 + 32; ++f) s += pooled[f] * Wo1[f * 64 + o];
        red[part * 64 + o] = s;
    }
    __syncthreads();
    if (tid < 64) {
        r1[tid] = elu1(bo1[tid] + red[tid] + red[64 + tid] + red[128 + tid] + red[192 + tid]);
    }
    __syncthreads();
    if (tid < 128) {
        const int o = tid & 31, part = tid >> 5;
        float s = 0.f;
        for (int f = part * 16; f < part * 16 + 16; ++f) s += r1[f] * Wo2[f * 32 + o];
        red[part * 32 + o] = s;
    }
    __syncthreads();
    if (tid < 32) {
        r2[tid] = elu1(bo2[tid] + red[tid] + red[32 + tid] + red[64 + tid] + red[96 + tid]);
    }
    __syncthreads();
    if (tid < 32) {
        float a = bo3[tid];
        for (int f = 0; f < 32; ++f) a += r2[f] * Wo3[f * 32 + tid];
        r3[tid] = elu1(a);
    }
    __syncthreads();
    if (tid < 8) {
        float a = bo4[tid];
        for (int f = 0; f < 32; ++f) a += r3[f] * Wo4[f * 8 + tid];
        out[g * 8 + tid] = a;
    }
}

extern "C" void kernel_launch(void* const* d_in, const int* in_sizes, int n_in,
                              void* d_out, int out_size, void* d_ws, size_t ws_size,
                              hipStream_t stream) {
    dgcnn_kernel<<<NG, 512, 0, stream>>>(
        (const float*)d_in[0],                            // x_pf
        (const float*)d_in[2],  (const float*)d_in[3],    // W1, b1
        (const float*)d_in[4],  (const float*)d_in[5],    // W2, b2
        (const float*)d_in[6],  (const float*)d_in[7],    // Wc, bc
        (const float*)d_in[8],  (const float*)d_in[9],    // Wo1, bo1
        (const float*)d_in[10], (const float*)d_in[11],   // Wo2, bo2
        (const float*)d_in[12], (const float*)d_in[13],   // Wo3, bo3
        (const float*)d_in[14], (const float*)d_in[15],   // Wo4, bo4
        (float*)d_out);
}

// Round 3
// 94.579 us; speedup vs baseline: 1.5990x; 1.4332x over previous
//
#include <hip/hip_runtime.h>
#include <hip/hip_bf16.h>
#include <math.h>

#define NG  256
#define NN  64
#define KK  24
#define HID 128
#define FP  132   // fp32 LDS row stride (floats)
#define KP  136   // bf16 LDS row stride (shorts): 272B, 16B-aligned, even bank spread
#define DP  68    // dmat row stride (floats)
#define SLAB (2*128*KP)          // shorts per staged matrix (hi+lo)
#define IMG_BYTES (3*SLAB*2)     // 208896 B in d_ws

typedef __attribute__((ext_vector_type(8)))  short bf16x8;
typedef __attribute__((ext_vector_type(4)))  float f32x4;
typedef __attribute__((ext_vector_type(16))) float f32x16;

__device__ __forceinline__ float elu1(float x){ return x > 0.f ? x : (expf(x)-1.f); }

__device__ __forceinline__ short bf_hi(float x){
    __hip_bfloat16 h = __float2bfloat16(x);
    return *(short*)&h;
}
__device__ __forceinline__ float bf_f(short s){
    __hip_bfloat16 h = *(__hip_bfloat16*)&s;
    return __bfloat162float(h);
}

// ---- prep: build transposed bf16 hi/lo weight images in d_ws ----
// slab s=0: W2 ; s=1: Wc rows [0,128) (U-half) ; s=2: Wc rows [128,256) (V-half)
// each slab: [hi: 128 n x 136 k][lo: 128 n x 136 k] shorts, img[n*KP+k] = W[k][n]
extern "C" __global__ void prep_kernel(const float* __restrict__ W2,
                                       const float* __restrict__ Wc,
                                       short* __restrict__ img)
{
    int idx = blockIdx.x * 256 + threadIdx.x;
    const int per = 128 * KP;
    if (idx >= 3 * per) return;
    int s = idx / per, r = idx % per;
    int n = r / KP, k = r % KP;
    float w = 0.f;
    if (k < 128) {
        if (s == 0)      w = W2[k*HID + n];
        else if (s == 1) w = Wc[k*HID + n];
        else             w = Wc[(HID + k)*HID + n];
    }
    short hs = bf_hi(w);
    short ls = bf_hi(w - bf_f(hs));
    img[s*SLAB + n*KP + k]       = hs;
    img[s*SLAB + per + n*KP + k] = ls;
}

// 3-pass (hi*hi + hi*lo + lo*hi) 32x32 GEMM tile: C[64x128] tile (tm,tn)
__device__ __forceinline__ f32x16 gemm32_3p(const short* fbhi, const short* fblo,
                                            const short* wTl, int tm, int tn, int lane)
{
    f32x16 c;
    #pragma unroll
    for (int i = 0; i < 16; ++i) c[i] = 0.f;
    const short* whi = wTl;
    const short* wlo = wTl + 128*KP;
    const int arow = tm*32 + (lane & 31);
    const int brow = tn*32 + (lane & 31);
    const int ko   = (lane >> 5) * 8;
    #pragma unroll
    for (int ks = 0; ks < 8; ++ks){
        bf16x8 ah = *(const bf16x8*)(fbhi + arow*KP + ks*16 + ko);
        bf16x8 al = *(const bf16x8*)(fblo + arow*KP + ks*16 + ko);
        bf16x8 bh = *(const bf16x8*)(whi  + brow*KP + ks*16 + ko);
        bf16x8 bl = *(const bf16x8*)(wlo  + brow*KP + ks*16 + ko);
        c = __builtin_amdgcn_mfma_f32_32x32x16_bf16(ah, bh, c, 0, 0, 0);
        c = __builtin_amdgcn_mfma_f32_32x32x16_bf16(ah, bl, c, 0, 0, 0);
        c = __builtin_amdgcn_mfma_f32_32x32x16_bf16(al, bh, c, 0, 0, 0);
    }
    return c;
}

// write 32x32 C-frag to fp32 LDS [row][FP]: col=tn*32+(lane&31), row=tm*32+(r&3)+8*(r>>2)+4*(lane>>5)
__device__ __forceinline__ void cwrite32(float* dst, const f32x16& c, int tm, int tn, int lane)
{
    const int col   = tn*32 + (lane & 31);
    const int rbase = tm*32 + 4*(lane >> 5);
    #pragma unroll
    for (int r = 0; r < 16; ++r){
        dst[(rbase + (r & 3) + 8*(r >> 2))*FP + col] = c[r];
    }
}

__device__ __forceinline__ void stage_slab(const short* src, short* wT, int tid)
{
    const uint4* s = (const uint4*)src;
    uint4* d = (uint4*)wT;
    for (int i = tid; i < SLAB/8; i += 512) d[i] = s[i];
}

// fallback: transpose+convert directly from global W (slow, only if ws too small)
__device__ __forceinline__ void stage_direct(const float* W, int rowoff, short* wT, int tid)
{
    for (int i = tid; i < 128*KP; i += 512){
        int n = i / KP, k = i % KP;
        float w = (k < 128) ? W[(rowoff + k)*HID + n] : 0.f;
        short hs = bf_hi(w);
        short ls = bf_hi(w - bf_f(hs));
        wT[n*KP + k]            = hs;
        wT[128*KP + n*KP + k]   = ls;
    }
}

extern "C" __global__ void __launch_bounds__(512, 2)
dgcnn_kernel(const float* __restrict__ x_pf,
             const float* __restrict__ W1, const float* __restrict__ b1,
             const float* __restrict__ W2, const float* __restrict__ b2,
             const float* __restrict__ Wc, const float* __restrict__ bc,
             const float* __restrict__ Wo1, const float* __restrict__ bo1,
             const float* __restrict__ Wo2, const float* __restrict__ bo2,
             const float* __restrict__ Wo3, const float* __restrict__ bo3,
             const float* __restrict__ Wo4, const float* __restrict__ bo4,
             const short* __restrict__ img, int use_img,
             float* __restrict__ out)
{
    __shared__ __align__(16) float feat[NN*FP];      // 33792 B
    __shared__ __align__(16) short fbhi[NN*KP];      // 17408 B
    __shared__ __align__(16) short fblo[NN*KP];      // 17408 B
    __shared__ __align__(16) short wT[SLAB];         // 69632 B; later holds V fp32 [0..33792) + U fp32 [33792..67584)
    __shared__ __align__(16) float dmat[NN*DP];      // 17408 B; later pooled/red/r1/r2/r3
    __shared__ int knn[NN*KK];                       // 6144 B
    __shared__ float sq[NN];                         // 256 B
    // total 162048 B

    const int tid  = threadIdx.x;
    const int g    = blockIdx.x;
    const int lane = tid & 63;
    const int wv   = tid >> 6;          // 0..7
    const int hq   = tid & 31;          // h-quad
    const int ngp  = tid >> 5;          // 0..15
    const int h0   = hq * 4;
    const int n0   = ngp * 4;
    const int tm   = wv & 1;            // 32-row tile
    const int tn   = wv >> 1;           // 32-col tile

    // batch_pf output
    if (tid < NN) out[NG*8 + g*NN + tid] = (float)g;

    // ---- W1: h = elu(x@W1+b1) -> feat (VALU, x from global/L1) ----
    {
        float acc[4][4];
        float4 bv = *(const float4*)(b1 + h0);
        #pragma unroll
        for (int r = 0; r < 4; ++r){ acc[r][0]=bv.x; acc[r][1]=bv.y; acc[r][2]=bv.z; acc[r][3]=bv.w; }
        #pragma unroll
        for (int f = 0; f < 15; ++f){
            float4 w = *(const float4*)(W1 + f*HID + h0);
            #pragma unroll
            for (int r = 0; r < 4; ++r){
                float xv = x_pf[g*NN*15 + (n0 + r)*15 + f];
                acc[r][0] += xv*w.x; acc[r][1] += xv*w.y;
                acc[r][2] += xv*w.z; acc[r][3] += xv*w.w;
            }
        }
        #pragma unroll
        for (int r = 0; r < 4; ++r){
            float4 o;
            o.x = elu1(acc[r][0]); o.y = elu1(acc[r][1]);
            o.z = elu1(acc[r][2]); o.w = elu1(acc[r][3]);
            *(float4*)(feat + (n0 + r)*FP + h0) = o;
        }
    }
    __syncthreads();

    // ---- convert h1 -> hi/lo ----
    {
        const int n = tid >> 3, k0 = (tid & 7)*16;
        #pragma unroll
        for (int half = 0; half < 2; ++half){
            bf16x8 hv, lv;
            #pragma unroll
            for (int j = 0; j < 8; ++j){
                float x = feat[n*FP + k0 + half*8 + j];
                short hs = bf_hi(x);
                short ls = bf_hi(x - bf_f(hs));
                hv[j] = hs; lv[j] = ls;
            }
            *(bf16x8*)(fbhi + n*KP + k0 + half*8) = hv;
            *(bf16x8*)(fblo + n*KP + k0 + half*8) = lv;
        }
    }
    __syncthreads();

    // ---- W2 GEMM (MFMA 3-pass): feat = elu(h1@W2 + b2) ----
    if (use_img) stage_slab(img + 0*SLAB, wT, tid); else stage_direct(W2, 0, wT, tid);
    __syncthreads();
    {
        f32x16 hc = gemm32_3p(fbhi, fblo, wT, tm, tn, lane);
        const int col = tn*32 + (lane & 31);
        const float bb = b2[col];
        const int rbase = tm*32 + 4*(lane >> 5);
        #pragma unroll
        for (int r = 0; r < 16; ++r){
            feat[(rbase + (r & 3) + 8*(r >> 2))*FP + col] = elu1(hc[r] + bb);
        }
    }
    __syncthreads();

    // ==== 3 EdgeConv layers ====
    for (int layer = 0; layer < 3; ++layer){
        // -- convert feat -> hi/lo, and squared norms --
        {
            const int n = tid >> 3, k0 = (tid & 7)*16;
            #pragma unroll
            for (int half = 0; half < 2; ++half){
                bf16x8 hv, lv;
                #pragma unroll
                for (int j = 0; j < 8; ++j){
                    float x = feat[n*FP + k0 + half*8 + j];
                    short hs = bf_hi(x);
                    short ls = bf_hi(x - bf_f(hs));
                    hv[j] = hs; lv[j] = lv[j] = ls;
                }
                *(bf16x8*)(fbhi + n*KP + k0 + half*8) = hv;
                *(bf16x8*)(fblo + n*KP + k0 + half*8) = lv;
            }
            if (tid < 256){
                const int row = tid >> 2, q = tid & 3;
                float s = 0.f;
                for (int f4 = q*8; f4 < q*8 + 8; ++f4){
                    float4 v = *(const float4*)(feat + row*FP + f4*4);
                    s += v.x*v.x + v.y*v.y + v.z*v.z + v.w*v.w;
                }
                s += __shfl_xor(s, 1, 64);
                s += __shfl_xor(s, 2, 64);
                if (q == 0) sq[row] = s;
            }
        }
        __syncthreads();

        // -- pairwise distances via MFMA (16x16x32, hi/lo 3-pass), 2 tiles/wave --
        {
            f32x4 dc0, dc1;
            #pragma unroll
            for (int i = 0; i < 4; ++i){ dc0[i] = 0.f; dc1[i] = 0.f; }
            const int t0 = wv*2, t1 = wv*2 + 1;
            const int tm0 = t0 >> 2, tn0 = t0 & 3;
            const int tm1 = t1 >> 2, tn1 = t1 & 3;
            const int rA0 = tm0*16 + (lane & 15), rB0 = tn0*16 + (lane & 15);
            const int rA1 = tm1*16 + (lane & 15), rB1 = tn1*16 + (lane & 15);
            const int ko  = (lane >> 4) * 8;
            #pragma unroll
            for (int ks = 0; ks < 4; ++ks){
                bf16x8 ah0 = *(const bf16x8*)(fbhi + rA0*KP + ks*32 + ko);
                bf16x8 al0 = *(const bf16x8*)(fblo + rA0*KP + ks*32 + ko);
                bf16x8 bh0 = *(const bf16x8*)(fbhi + rB0*KP + ks*32 + ko);
                bf16x8 bl0 = *(const bf16x8*)(fblo + rB0*KP + ks*32 + ko);
                dc0 = __builtin_amdgcn_mfma_f32_16x16x32_bf16(ah0, bh0, dc0, 0,0,0);
                dc0 = __builtin_amdgcn_mfma_f32_16x16x32_bf16(ah0, bl0, dc0, 0,0,0);
                dc0 = __builtin_amdgcn_mfma_f32_16x16x32_bf16(al0, bh0, dc0, 0,0,0);
                bf16x8 ah1 = *(const bf16x8*)(fbhi + rA1*KP + ks*32 + ko);
                bf16x8 al1 = *(const bf16x8*)(fblo + rA1*KP + ks*32 + ko);
                bf16x8 bh1 = *(const bf16x8*)(fbhi + rB1*KP + ks*32 + ko);
                bf16x8 bl1 = *(const bf16x8*)(fblo + rB1*KP + ks*32 + ko);
                dc1 = __builtin_amdgcn_mfma_f32_16x16x32_bf16(ah1, bh1, dc1, 0,0,0);
                dc1 = __builtin_amdgcn_mfma_f32_16x16x32_bf16(ah1, bl1, dc1, 0,0,0);
                dc1 = __builtin_amdgcn_mfma_f32_16x16x32_bf16(al1, bh1, dc1, 0,0,0);
            }
            #pragma unroll
            for (int e = 0; e < 4; ++e){
                const int ra = tm0*16 + (lane >> 4)*4 + e, ca = tn0*16 + (lane & 15);
                dmat[ra*DP + ca] = sq[ra] + sq[ca] - 2.f*dc0[e];
                const int rb = tm1*16 + (lane >> 4)*4 + e, cb = tn1*16 + (lane & 15);
                dmat[rb*DP + cb] = sq[rb] + sq[cb] - 2.f*dc1[e];
            }
        }
        __syncthreads();

        // -- kNN membership via rank counting (ties -> lower index) --
        {
            for (int p = 0; p < 8; ++p){
                const int r = wv*8 + p;
                const float dm = dmat[r*DP + lane];
                float4 rv[16];
                #pragma unroll
                for (int q = 0; q < 16; ++q) rv[q] = *(const float4*)(dmat + r*DP + q*4);
                int rank = 0;
                #pragma unroll
                for (int q = 0; q < 16; ++q){
                    const int m0 = q*4;
                    rank += (rv[q].x < dm) || (rv[q].x == dm && (m0+0) < lane);
                    rank += (rv[q].y < dm) || (rv[q].y == dm && (m0+1) < lane);
                    rank += (rv[q].z < dm) || (rv[q].z == dm && (m0+2) < lane);
                    rank += (rv[q].w < dm) || (rv[q].w == dm && (m0+3) < lane);
                }
                const unsigned long long mask = __ballot(rank < KK);
                if (rank < KK){
                    const int c = __popcll(mask & ((1ULL << lane) - 1ULL));
                    knn[r*KK + c] = lane;
                }
            }
        }
        __syncthreads();

        // -- U GEMM --
        if (use_img) stage_slab(img + 1*SLAB, wT, tid); else stage_direct(Wc, 0, wT, tid);
        __syncthreads();
        f32x16 uc = gemm32_3p(fbhi, fblo, wT, tm, tn, lane);
        __syncthreads();
        // -- V GEMM --
        if (use_img) stage_slab(img + 2*SLAB, wT, tid); else stage_direct(Wc, HID, wT, tid);
        __syncthreads();
        f32x16 vc = gemm32_3p(fbhi, fblo, wT, tm, tn, lane);
        __syncthreads();   // all reads of wT done before overwrite
        {
            float* Vl = (float*)wT;
            float* Ul = Vl + NN*FP;
            cwrite32(Ul, uc, tm, tn, lane);
            cwrite32(Vl, vc, tm, tn, lane);
        }
        __syncthreads();

        // -- combine: feat[n,h] = elu(U - V_self + bc + max_k V[knn]) --
        {
            const float* Vl = (const float*)wT;
            const float* Ul = Vl + NN*FP;
            float4 bcv = *(const float4*)(bc + h0);
            #pragma unroll
            for (int r = 0; r < 4; ++r){
                const int n = n0 + r;
                float4 mx = make_float4(-1e30f, -1e30f, -1e30f, -1e30f);
                for (int k = 0; k < KK; ++k){
                    int j = knn[n*KK + k];
                    float4 v = *(const float4*)(Vl + j*FP + h0);
                    mx.x = fmaxf(mx.x, v.x); mx.y = fmaxf(mx.y, v.y);
                    mx.z = fmaxf(mx.z, v.z); mx.w = fmaxf(mx.w, v.w);
                }
                float4 u  = *(const float4*)(Ul + n*FP + h0);
                float4 vn = *(const float4*)(Vl + n*FP + h0);
                float4 o;
                o.x = elu1(u.x - vn.x + bcv.x + mx.x);
                o.y = elu1(u.y - vn.y + bcv.y + mx.y);
                o.z = elu1(u.z - vn.z + bcv.z + mx.z);
                o.w = elu1(u.w - vn.w + bcv.w + mx.w);
                *(float4*)(feat + n*FP + h0) = o;
            }
        }
        __syncthreads();
    }

    // ==== pooled + head (scratch aliased into dmat, which is dead now) ====
    float* pooled = dmat;            // 128
    float* red    = dmat + 128;      // 512
    float* hr1    = dmat + 640;      // 64
    float* hr2    = dmat + 704;      // 32
    float* hr3    = dmat + 736;      // 32

    {
        const int pq = tid >> 7, ch = tid & 127;
        float s = 0.f;
        for (int n = pq*16; n < pq*16 + 16; ++n) s += feat[n*FP + ch];
        red[pq*HID + ch] = s;
    }
    __syncthreads();
    if (tid < HID) pooled[tid] = red[tid] + red[HID + tid] + red[2*HID + tid] + red[3*HID + tid];
    __syncthreads();
    if (tid < 256){
        const int o = tid & 63, part = tid >> 6;
        float s = 0.f;
        for (int f = part*32; f < part*32 + 32; ++f) s += pooled[f] * Wo1[f*64 + o];
        red[part*64 + o] = s;
    }
    __syncthreads();
    if (tid < 64) hr1[tid] = elu1(bo1[tid] + red[tid] + red[64+tid] + red[128+tid] + red[192+tid]);
    __syncthreads();
    if (tid < 128){
        const int o = tid & 31, part = tid >> 5;
        float s = 0.f;
        for (int f = part*16; f < part*16 + 16; ++f) s += hr1[f] * Wo2[f*32 + o];
        red[part*32 + o] = s;
    }
    __syncthreads();
    if (tid < 32) hr2[tid] = elu1(bo2[tid] + red[tid] + red[32+tid] + red[64+tid] + red[96+tid]);
    __syncthreads();
    if (tid < 32){
        float a = bo3[tid];
        for (int f = 0; f < 32; ++f) a += hr2[f] * Wo3[f*32 + tid];
        hr3[tid] = elu1(a);
    }
    __syncthreads();
    if (tid < 8){
        float a = bo4[tid];
        for (int f = 0; f < 32; ++f) a += hr3[f] * Wo4[f*8 + tid];
        out[g*8 + tid] = a;
    }
}

extern "C" void kernel_launch(void* const* d_in, const int* in_sizes, int n_in,
                              void* d_out, int out_size, void* d_ws, size_t ws_size,
                              hipStream_t stream) {
    short* img = (short*)d_ws;
    const int use_img = (ws_size >= (size_t)IMG_BYTES) ? 1 : 0;
    if (use_img) {
        const int total = 3 * 128 * KP;
        prep_kernel<<<(total + 255)/256, 256, 0, stream>>>(
            (const float*)d_in[4], (const float*)d_in[6], img);
    }
    dgcnn_kernel<<<NG, 512, 0, stream>>>(
        (const float*)d_in[0],
        (const float*)d_in[2],  (const float*)d_in[3],
        (const float*)d_in[4],  (const float*)d_in[5],
        (const float*)d_in[6],  (const float*)d_in[7],
        (const float*)d_in[8],  (const float*)d_in[9],
        (const float*)d_in[10], (const float*)d_in[11],
        (const float*)d_in[12], (const float*)d_in[13],
        (const float*)d_in[14], (const float*)d_in[15],
        img, use_img,
        (float*)d_out);
}